// Round 16
// baseline (364.532 us; speedup 1.0000x reference)
//
#include <hip/hip_runtime.h>

#define F_DIMC 64
#define K_DIMC 16
#define NGRAPH 64
#define NXCD 8
#define PERG 1600                          // N/B, fixed geometry
#define WSTRIDE 17                         // w row stride (16 comps + deg), bank-spread
#define SX_WAVES 8
#define SX_SPLIT 8
#define NB_SEL 400                         // N/256
#define NB_CHUNK 256                       // histogram/scatter chunks
#define CHUNK_I4 800                       // int4s per chunk (256*800 = E/4)
#define AGG_BLOCKS 64                      // 1 per graph
#define ADJ_OFF (NGRAPH * K_DIMC * F_DIMC)
#define LOSS_OFF (ADJ_OFF + NGRAPH * K_DIMC * K_DIMC)
#define ZERO_BYTES 394240

// ---------------- workspace layout (bytes) ----------------
// zeroed each call by k_zero: [0, 394240)
//   [0,256)          den (float[64])
//   [256,512)        donecnt (int) + pad
//   [512,768)        lossws (float[2]) + pad
//   [768,1024)       pad
//   [1024,66560)     dense_raw (float[64*256])
//   [66560,132096)   ssbuf (float[64*256])
//   [132096,394240)  sxbuf (float[64*1024])
// not zeroed:
//   [394240,394496)    offsets (int[64])
//   [394496,394752)    gtot (int[64])
//   [394752,460288)    blockhist (int[256][64])
//   [460288,525824)    chunkbase (int[256][64])
//   [525824,7079424)   sel (float[N*16])
//   [7079424,13633024) sorted (uint2[E])
//   [13633024,20186624) wbuf (float[N*16])
//   [20186624,20596224) degbuf (float[N])
// (ws_size >> 21MB: harness poison fill writes 268MB)

__global__ __launch_bounds__(256) void k_zero(float4* __restrict__ p, int n4) {
    int i = blockIdx.x * 256 + threadIdx.x;
    int stride = gridDim.x * 256;
    for (; i < n4; i += stride) p[i] = make_float4(0.f, 0.f, 0.f, 0.f);
}

// ---- fused: selection (blocks [0,NB_SEL)) || per-chunk histogram (rest) ----
__global__ __launch_bounds__(256) void k_sel_hist(const float* __restrict__ node_attr,
                                                  const float* __restrict__ W,
                                                  const float* __restrict__ bias,
                                                  const int* __restrict__ row,
                                                  float* __restrict__ sel,
                                                  int* __restrict__ blockhist,
                                                  int N, int perG) {
    int t = threadIdx.x;
    if (blockIdx.x < NB_SEL) {
        __shared__ float sW[K_DIMC][F_DIMC];
        __shared__ float sb[K_DIMC];
        for (int idx = t; idx < F_DIMC * K_DIMC; idx += 256) {
            int f = idx / K_DIMC, k = idx % K_DIMC;
            sW[k][f] = W[idx];
        }
        if (t < K_DIMC) sb[t] = bias[t];
        __syncthreads();
        int n = blockIdx.x * 256 + t;
        if (n >= N) return;

        const float4* xr = (const float4*)(node_attr + (size_t)n * F_DIMC);
        float4 x[F_DIMC / 4];
#pragma unroll
        for (int f4 = 0; f4 < F_DIMC / 4; ++f4) x[f4] = xr[f4];

        float logits[K_DIMC];
#pragma unroll
        for (int k = 0; k < K_DIMC; ++k) {
            const float4* wk = (const float4*)&sW[k][0];
            float acc = sb[k];
#pragma unroll
            for (int f4 = 0; f4 < F_DIMC / 4; ++f4) {
                float4 w = wk[f4];
                acc += x[f4].x * w.x + x[f4].y * w.y + x[f4].z * w.z + x[f4].w * w.w;
            }
            logits[k] = acc;
        }
        float m = logits[0];
#pragma unroll
        for (int k = 1; k < K_DIMC; ++k) m = fmaxf(m, logits[k]);
        float sum = 0.f;
#pragma unroll
        for (int k = 0; k < K_DIMC; ++k) {
            float e = __expf(logits[k] - m);
            logits[k] = e;
            sum += e;
        }
        float inv = 1.f / sum;
        float4* sd = (float4*)(sel + (size_t)n * K_DIMC);
#pragma unroll
        for (int k4 = 0; k4 < K_DIMC / 4; ++k4) {
            float4 v;
            v.x = logits[4 * k4 + 0] * inv;
            v.y = logits[4 * k4 + 1] * inv;
            v.z = logits[4 * k4 + 2] * inv;
            v.w = logits[4 * k4 + 3] * inv;
            sd[k4] = v;
        }
    } else {
        __shared__ int lh[NGRAPH];
        int h = blockIdx.x - NB_SEL;                 // 0..255, static chunk
        if (t < NGRAPH) lh[t] = 0;
        __syncthreads();
        for (int i = t; i < CHUNK_I4; i += 256) {
            int4 r4 = ((const int4*)row)[h * CHUNK_I4 + i];
            atomicAdd(&lh[r4.x / perG], 1);
            atomicAdd(&lh[r4.y / perG], 1);
            atomicAdd(&lh[r4.z / perG], 1);
            atomicAdd(&lh[r4.w / perG], 1);
        }
        __syncthreads();
        if (t < NGRAPH) blockhist[h * NGRAPH + t] = lh[t];
    }
}

// ---- per-graph exclusive scan over 256 chunks: chunkbase[b][g], gtot[g] ----
__global__ __launch_bounds__(256) void k_chunkscan(const int* __restrict__ blockhist,
                                                   int* __restrict__ chunkbase,
                                                   int* __restrict__ gtot) {
    int g = blockIdx.x;
    int t = threadIdx.x;                 // 0..255 = chunk index
    int lane = t & 63;
    int wid = t >> 6;
    int v = blockhist[t * NGRAPH + g];
    int s = v;
#pragma unroll
    for (int d = 1; d < 64; d <<= 1) {
        int o = __shfl_up(s, d);
        if (lane >= d) s += o;
    }
    __shared__ int wsum[4];
    if (lane == 63) wsum[wid] = s;
    __syncthreads();
    int pre = 0;
#pragma unroll
    for (int w = 0; w < 4; ++w) pre += (w < wid) ? wsum[w] : 0;
    int incl = s + pre;
    chunkbase[t * NGRAPH + g] = incl - v;
    if (t == 255) gtot[g] = incl;
}

// ---- deterministic scatter: static chunks; LDS position counters only ----
__global__ __launch_bounds__(256) void k_scatter(const int* __restrict__ row,
                                                 const int* __restrict__ col,
                                                 const int* __restrict__ gtot,
                                                 const int* __restrict__ chunkbase,
                                                 int* __restrict__ offsets,
                                                 uint2* __restrict__ sorted,
                                                 int perG) {
    __shared__ int base_[NGRAPH];
    __shared__ int lcnt[NGRAPH];
    int t = threadIdx.x;
    int h = blockIdx.x;                  // 0..255, same chunk as hist
    if (t < 64) {
        int v = gtot[t];
        int s = v;
#pragma unroll
        for (int d = 1; d < 64; d <<= 1) {
            int o = __shfl_up(s, d);
            if (t >= d) s += o;
        }
        int offs = s - v;                // exclusive scan = graph base
        base_[t] = offs + chunkbase[h * NGRAPH + t];
        lcnt[t] = 0;
        if (h == 0) offsets[t] = offs;
    }
    __syncthreads();
    for (int i = t; i < CHUNK_I4; i += 256) {
        int e4 = h * CHUNK_I4 + i;
        int4 r4 = ((const int4*)row)[e4];
        int4 c4 = ((const int4*)col)[e4];
        int rr[4] = {r4.x, r4.y, r4.z, r4.w};
        int cc[4] = {c4.x, c4.y, c4.z, c4.w};
#pragma unroll
        for (int u = 0; u < 4; ++u) {
            int g = rr[u] / perG;
            int lpos = atomicAdd(&lcnt[g], 1);
            sorted[(size_t)base_[g] + lpos] = make_uint2((unsigned)rr[u], (unsigned)cc[u]);
        }
    }
}

// ---- k_agg: W[n,:] = sum_{e: row=n} sel[col_e,:], deg[n] = edge count.
// 64 blocks (1/graph, XCD-grouped), 512 thr. LDS w[1600][17] (deg in pad col).
// Per 16 edges per wave: ONE f4 gather + 4 ds_add (vs 2 mem-instr PER EDGE in
// the outer-product formulation -> ~8x fewer LDS ops; rounds 12-15 evidence).
// Lane l: edge ei=l>>2 of subgroup, components sub=(l&3)*4..+3.
__global__ __launch_bounds__(512) void k_agg(const uint2* __restrict__ sorted,
                                             const int* __restrict__ offsets,
                                             const int* __restrict__ gtot,
                                             const float* __restrict__ sel,
                                             float* __restrict__ wbuf,
                                             float* __restrict__ degbuf) {
    __shared__ float w[PERG * WSTRIDE];      // 108800 B
    int b = blockIdx.x;                      // 0..63
    int xcd = b & (NXCD - 1);
    int g = xcd * (NGRAPH / NXCD) + (b >> 3);
    int t = threadIdx.x;
    for (int i = t; i < PERG * WSTRIDE; i += 512) w[i] = 0.f;
    __syncthreads();

    int start = offsets[g];
    int cnt = gtot[g];
    int wid = t >> 6;
    int lane = t & 63;
    int sub = lane & 3;
    int ei = lane >> 2;                      // edge index within 16-edge subgroup
    int gnode = g * PERG;

    int nBatch = (cnt + 63) >> 6;
    for (int bb = wid; bb < nBatch; bb += 8) {
        int e0 = bb << 6;
        int nb = cnt - e0;
        if (nb > 64) nb = 64;
        uint2 pr = sorted[start + e0 + (lane < nb ? lane : nb - 1)];
        int rloc = ((int)pr.x - gnode) * WSTRIDE;   // LDS row base
        int cglob = (int)pr.y * K_DIMC;             // global sel float base
#pragma unroll
        for (int s = 0; s < 4; ++s) {
            int src = s * 16 + ei;
            int cb = __shfl(cglob, src);
            int rb = __shfl(rloc, src);
            if (src < nb) {
                float4 v = *(const float4*)(sel + cb + sub * 4);
                atomicAdd(&w[rb + sub * 4 + 0], v.x);
                atomicAdd(&w[rb + sub * 4 + 1], v.y);
                atomicAdd(&w[rb + sub * 4 + 2], v.z);
                atomicAdd(&w[rb + sub * 4 + 3], v.w);
                if (sub == 0) atomicAdd(&w[rb + 16], 1.0f);
            }
        }
    }
    __syncthreads();
    // write out w (f4 x4) + deg, per node
    for (int n = t; n < PERG; n += 512) {
        const float* srcw = &w[n * WSTRIDE];
        float4* dst = (float4*)(wbuf + (size_t)(gnode + n) * K_DIMC);
        dst[0] = make_float4(srcw[0], srcw[1], srcw[2], srcw[3]);
        dst[1] = make_float4(srcw[4], srcw[5], srcw[6], srcw[7]);
        dst[2] = make_float4(srcw[8], srcw[9], srcw[10], srcw[11]);
        dst[3] = make_float4(srcw[12], srcw[13], srcw[14], srcw[15]);
        degbuf[gnode + n] = srcw[16];
    }
}

// ---- SX/SS + adjacency phase-2 + den: grid (SX_SPLIT, NGRAPH), 8 waves.
// Per node adds: accadj[c] += sel[n][k] * wbuf[n][j0+c]  (dense_adj = S^T W),
// qacc += deg[n]*a^2 (den; sum over 64 lanes = 4*den).
__global__ __launch_bounds__(512) void k_sx(const float* __restrict__ sel,
                                            const float* __restrict__ x,
                                            const float* __restrict__ wbuf,
                                            const float* __restrict__ degbuf,
                                            float* __restrict__ ssbuf,
                                            float* __restrict__ sxbuf,
                                            float* __restrict__ dense_raw,
                                            float* __restrict__ den, int perG) {
    int g = blockIdx.y;
    int wid = threadIdx.x >> 6;
    int wslot = blockIdx.x * SX_WAVES + wid;     // 0..63
    int lane = threadIdx.x & 63;
    int k = lane >> 2;
    int sub = lane & 3;
    int f0 = sub * 16;
    int j0 = sub * 4;
    float accss[4] = {0.f, 0.f, 0.f, 0.f};
    float accadj[4] = {0.f, 0.f, 0.f, 0.f};
    float qacc = 0.f;
    float accsx[16];
#pragma unroll
    for (int j = 0; j < 16; ++j) accsx[j] = 0.f;
    size_t base = (size_t)g * perG;
    int stride = SX_SPLIT * SX_WAVES;            // 64
#pragma unroll 2
    for (int nn = wslot; nn < perG; nn += stride) {
        size_t node = base + nn;
        float a = sel[node * K_DIMC + k];
        float4 s4 = *(const float4*)(sel + node * K_DIMC + j0);
        float4 wv = *(const float4*)(wbuf + node * K_DIMC + j0);
        float dg = degbuf[node];
        accss[0] += a * s4.x;
        accss[1] += a * s4.y;
        accss[2] += a * s4.z;
        accss[3] += a * s4.w;
        accadj[0] += a * wv.x;
        accadj[1] += a * wv.y;
        accadj[2] += a * wv.z;
        accadj[3] += a * wv.w;
        qacc = fmaf(dg * a, a, qacc);
        const float4* xv = (const float4*)(x + node * F_DIMC + f0);
#pragma unroll
        for (int j = 0; j < 4; ++j) {
            float4 v = xv[j];
            accsx[4 * j + 0] += a * v.x;
            accsx[4 * j + 1] += a * v.y;
            accsx[4 * j + 2] += a * v.z;
            accsx[4 * j + 3] += a * v.w;
        }
    }
    __shared__ float lsx[SX_WAVES][K_DIMC * F_DIMC];  // 32 KB
    __shared__ float lss[SX_WAVES][256];              // 8 KB
    __shared__ float ladj[SX_WAVES][256];             // 8 KB
    __shared__ float qred[SX_WAVES];
#pragma unroll
    for (int j4 = 0; j4 < 4; ++j4) {
        *(float4*)&lsx[wid][k * F_DIMC + f0 + 4 * j4] =
            make_float4(accsx[4 * j4], accsx[4 * j4 + 1], accsx[4 * j4 + 2], accsx[4 * j4 + 3]);
    }
    *(float4*)&lss[wid][k * K_DIMC + j0] = make_float4(accss[0], accss[1], accss[2], accss[3]);
    *(float4*)&ladj[wid][k * K_DIMC + j0] = make_float4(accadj[0], accadj[1], accadj[2], accadj[3]);
#pragma unroll
    for (int off = 32; off > 0; off >>= 1) qacc += __shfl_down(qacc, off);
    if (lane == 0) qred[wid] = qacc;
    __syncthreads();
    for (int c = threadIdx.x; c < K_DIMC * F_DIMC; c += 512) {
        float s = 0.f;
#pragma unroll
        for (int w = 0; w < SX_WAVES; ++w) s += lsx[w][c];
        atomicAdd(sxbuf + (size_t)g * (K_DIMC * F_DIMC) + c, s);
    }
    if (threadIdx.x < 256) {
        int c = threadIdx.x;
        float s = 0.f, sa = 0.f;
#pragma unroll
        for (int w = 0; w < SX_WAVES; ++w) { s += lss[w][c]; sa += ladj[w][c]; }
        atomicAdd(ssbuf + g * 256 + c, s);
        atomicAdd(dense_raw + g * 256 + c, sa);
    }
    if (threadIdx.x == 256) {
        float qs = 0.f;
#pragma unroll
        for (int w = 0; w < SX_WAVES; ++w) qs += qred[w];
        atomicAdd(den + g, qs * 0.25f);
    }
}

// ---- finalize: normalize adj, copy SX to out, losses via ws + last-block write ----
__global__ __launch_bounds__(256) void k_fin(const float* __restrict__ dense_raw,
                                             const float* __restrict__ ssbuf,
                                             const float* __restrict__ sxbuf,
                                             const float* __restrict__ den,
                                             float* __restrict__ lossws,
                                             int* __restrict__ donecnt,
                                             float* __restrict__ out) {
    int g = blockIdx.x;
    int c = threadIdx.x;
    int k = c >> 4, j = c & 15;
    int lane = threadIdx.x & 63;
    int wid = threadIdx.x >> 6;

    ((float4*)(out + (size_t)g * (K_DIMC * F_DIMC)))[c] =
        ((const float4*)(sxbuf + (size_t)g * (K_DIMC * F_DIMC)))[c];

    float a = dense_raw[g * 256 + c];
    float s = a;
    s += __shfl_xor(s, 1);
    s += __shfl_xor(s, 2);
    s += __shfl_xor(s, 4);
    s += __shfl_xor(s, 8);
    __shared__ float dvrow[K_DIMC];
    if (j == 0) dvrow[k] = sqrtf(s) + 1e-15f;
    __syncthreads();
    float v = a / (dvrow[k] * dvrow[j]);
    out[ADJ_OFF + g * 256 + c] = v;

    float ss = ssbuf[g * 256 + c];
    float tt = (k == j) ? v : 0.f;
    float n2 = ss * ss;
#pragma unroll
    for (int off = 32; off > 0; off >>= 1) {
        tt += __shfl_down(tt, off);
        n2 += __shfl_down(n2, off);
    }
    __shared__ float redt[4], redn[4];
    if (lane == 0) { redt[wid] = tt; redn[wid] = n2; }
    __syncthreads();
    float tr = redt[0] + redt[1] + redt[2] + redt[3];
    float nrm2 = redn[0] + redn[1] + redn[2] + redn[3];
    float invn = 1.f / sqrtf(nrm2);
    float d = ss * invn - ((k == j) ? 0.25f : 0.f);
    float o2 = d * d;
#pragma unroll
    for (int off = 32; off > 0; off >>= 1) o2 += __shfl_down(o2, off);
    __shared__ float redo[4];
    if (lane == 0) redo[wid] = o2;
    __syncthreads();
    if (threadIdx.x == 0) {
        float osum = redo[0] + redo[1] + redo[2] + redo[3];
        float og = sqrtf(osum);
        float mterm = -(tr / den[g]);
        atomicAdd(lossws + 0, mterm * (1.f / NGRAPH));
        atomicAdd(lossws + 1, og * (1.f / NGRAPH));
        __threadfence();
        int old = atomicAdd(donecnt, 1);
        if (old == NGRAPH - 1) {
            float l0 = atomicAdd(lossws + 0, 0.f);
            float l1 = atomicAdd(lossws + 1, 0.f);
            out[LOSS_OFF + 0] = l0;
            out[LOSS_OFF + 1] = l1;
        }
    }
}

extern "C" void kernel_launch(void* const* d_in, const int* in_sizes, int n_in,
                              void* d_out, int out_size, void* d_ws, size_t ws_size,
                              hipStream_t stream) {
    const float* node_attr = (const float*)d_in[0];
    const float* W = (const float*)d_in[1];
    const float* bias = (const float*)d_in[2];
    const int* edge_index = (const int*)d_in[3];
    int N = in_sizes[0] / F_DIMC;
    int E = in_sizes[3] / 2;
    int perG = N / NGRAPH;
    const int* row = edge_index;
    const int* col = edge_index + E;
    float* out = (float*)d_out;
    char* ws = (char*)d_ws;

    float* den = (float*)(ws + 0);
    int* donecnt = (int*)(ws + 256);
    float* lossws = (float*)(ws + 512);
    float* dense_raw = (float*)(ws + 1024);
    float* ssbuf = (float*)(ws + 66560);
    float* sxbuf = (float*)(ws + 132096);
    int* offsets = (int*)(ws + 394240);
    int* gtot = (int*)(ws + 394496);
    int* blockhist = (int*)(ws + 394752);
    int* chunkbase = (int*)(ws + 460288);
    float* sel = (float*)(ws + 525824);
    uint2* sorted = (uint2*)(ws + 7079424);
    float* wbuf = (float*)(ws + 13633024);
    float* degbuf = (float*)(ws + 20186624);

    k_zero<<<64, 256, 0, stream>>>((float4*)ws, ZERO_BYTES / 16);
    k_sel_hist<<<NB_SEL + NB_CHUNK, 256, 0, stream>>>(node_attr, W, bias, row, sel,
                                                      blockhist, N, perG);
    k_chunkscan<<<NGRAPH, 256, 0, stream>>>(blockhist, chunkbase, gtot);
    k_scatter<<<NB_CHUNK, 256, 0, stream>>>(row, col, gtot, chunkbase, offsets,
                                            sorted, perG);
    k_agg<<<AGG_BLOCKS, 512, 0, stream>>>(sorted, offsets, gtot, sel, wbuf, degbuf);
    k_sx<<<dim3(SX_SPLIT, NGRAPH), 512, 0, stream>>>(sel, node_attr, wbuf, degbuf,
                                                     ssbuf, sxbuf, dense_raw, den, perG);
    k_fin<<<NGRAPH, 256, 0, stream>>>(dense_raw, ssbuf, sxbuf, den, lossws, donecnt, out);
}

// Round 17
// 105.198 us; speedup vs baseline: 3.4652x; 3.4652x over previous
//
#include <hip/hip_runtime.h>

#define F_DIMC 64
#define K_DIMC 16
#define NGRAPH 64
#define NXCD 8
#define ADJ_SPLIT 32
#define SX_WAVES 8
#define SX_SPLIT 8
#define NB_SEL 400                         // N/256
#define NB_CHUNK 256                       // histogram/scatter chunks
#define CHUNK_I4 800                       // int4s per chunk (256*800 = E/4)
#define ADJ_OFF (NGRAPH * K_DIMC * F_DIMC)
#define LOSS_OFF (ADJ_OFF + NGRAPH * K_DIMC * K_DIMC)
#define ZERO_BYTES 394240

typedef __attribute__((ext_vector_type(4))) float vfloat4;

// ---------------- workspace layout (bytes) ----------------
// zeroed each call by k_zero: [0, 394240)
//   [0,256) den | [256,512) donecnt | [512,768) lossws | [768,1024) pad
//   [1024,66560) dense_raw | [66560,132096) ssbuf | [132096,394240) sxbuf
// not zeroed:
//   [394240,394496) offsets | [394496,394752) gtot
//   [394752,460288) blockhist | [460288,525824) chunkbase
//   [525824,7079424) sel (float[N*16]) | [7079424,13633024) sorted (uint2[E])

__global__ __launch_bounds__(256) void k_zero(float4* __restrict__ p, int n4) {
    int i = blockIdx.x * 256 + threadIdx.x;
    int stride = gridDim.x * 256;
    for (; i < n4; i += stride) p[i] = make_float4(0.f, 0.f, 0.f, 0.f);
}

// ---- fused: selection (blocks [0,NB_SEL)) || per-chunk histogram (rest) ----
__global__ __launch_bounds__(256) void k_sel_hist(const float* __restrict__ node_attr,
                                                  const float* __restrict__ W,
                                                  const float* __restrict__ bias,
                                                  const int* __restrict__ row,
                                                  float* __restrict__ sel,
                                                  int* __restrict__ blockhist,
                                                  int N, int perG) {
    int t = threadIdx.x;
    if (blockIdx.x < NB_SEL) {
        __shared__ float sW[K_DIMC][F_DIMC];
        __shared__ float sb[K_DIMC];
        for (int idx = t; idx < F_DIMC * K_DIMC; idx += 256) {
            int f = idx / K_DIMC, k = idx % K_DIMC;
            sW[k][f] = W[idx];
        }
        if (t < K_DIMC) sb[t] = bias[t];
        __syncthreads();
        int n = blockIdx.x * 256 + t;
        if (n >= N) return;

        const float4* xr = (const float4*)(node_attr + (size_t)n * F_DIMC);
        float4 x[F_DIMC / 4];
#pragma unroll
        for (int f4 = 0; f4 < F_DIMC / 4; ++f4) x[f4] = xr[f4];

        float logits[K_DIMC];
#pragma unroll
        for (int k = 0; k < K_DIMC; ++k) {
            const float4* wk = (const float4*)&sW[k][0];
            float acc = sb[k];
#pragma unroll
            for (int f4 = 0; f4 < F_DIMC / 4; ++f4) {
                float4 w = wk[f4];
                acc += x[f4].x * w.x + x[f4].y * w.y + x[f4].z * w.z + x[f4].w * w.w;
            }
            logits[k] = acc;
        }
        float m = logits[0];
#pragma unroll
        for (int k = 1; k < K_DIMC; ++k) m = fmaxf(m, logits[k]);
        float sum = 0.f;
#pragma unroll
        for (int k = 0; k < K_DIMC; ++k) {
            float e = __expf(logits[k] - m);
            logits[k] = e;
            sum += e;
        }
        float inv = 1.f / sum;
        float4* sd = (float4*)(sel + (size_t)n * K_DIMC);
#pragma unroll
        for (int k4 = 0; k4 < K_DIMC / 4; ++k4) {
            float4 v;
            v.x = logits[4 * k4 + 0] * inv;
            v.y = logits[4 * k4 + 1] * inv;
            v.z = logits[4 * k4 + 2] * inv;
            v.w = logits[4 * k4 + 3] * inv;
            sd[k4] = v;
        }
    } else {
        __shared__ int lh[NGRAPH];
        int h = blockIdx.x - NB_SEL;                 // 0..255, static chunk
        if (t < NGRAPH) lh[t] = 0;
        __syncthreads();
        for (int i = t; i < CHUNK_I4; i += 256) {
            int4 r4 = ((const int4*)row)[h * CHUNK_I4 + i];
            atomicAdd(&lh[r4.x / perG], 1);
            atomicAdd(&lh[r4.y / perG], 1);
            atomicAdd(&lh[r4.z / perG], 1);
            atomicAdd(&lh[r4.w / perG], 1);
        }
        __syncthreads();
        if (t < NGRAPH) blockhist[h * NGRAPH + t] = lh[t];
    }
}

// ---- per-graph exclusive scan over 256 chunks: chunkbase[b][g], gtot[g] ----
__global__ __launch_bounds__(256) void k_chunkscan(const int* __restrict__ blockhist,
                                                   int* __restrict__ chunkbase,
                                                   int* __restrict__ gtot) {
    int g = blockIdx.x;
    int t = threadIdx.x;                 // 0..255 = chunk index
    int lane = t & 63;
    int wid = t >> 6;
    int v = blockhist[t * NGRAPH + g];
    int s = v;
#pragma unroll
    for (int d = 1; d < 64; d <<= 1) {
        int o = __shfl_up(s, d);
        if (lane >= d) s += o;
    }
    __shared__ int wsum[4];
    if (lane == 63) wsum[wid] = s;
    __syncthreads();
    int pre = 0;
#pragma unroll
    for (int w = 0; w < 4; ++w) pre += (w < wid) ? wsum[w] : 0;
    int incl = s + pre;
    chunkbase[t * NGRAPH + g] = incl - v;
    if (t == 255) gtot[g] = incl;
}

// ---- deterministic scatter: static chunks; LDS position counters only ----
__global__ __launch_bounds__(256) void k_scatter(const int* __restrict__ row,
                                                 const int* __restrict__ col,
                                                 const int* __restrict__ gtot,
                                                 const int* __restrict__ chunkbase,
                                                 int* __restrict__ offsets,
                                                 uint2* __restrict__ sorted,
                                                 int perG) {
    __shared__ int base_[NGRAPH];
    __shared__ int lcnt[NGRAPH];
    int t = threadIdx.x;
    int h = blockIdx.x;                  // 0..255, same chunk as hist
    if (t < 64) {
        int v = gtot[t];
        int s = v;
#pragma unroll
        for (int d = 1; d < 64; d <<= 1) {
            int o = __shfl_up(s, d);
            if (t >= d) s += o;
        }
        int offs = s - v;                // exclusive scan = graph base
        base_[t] = offs + chunkbase[h * NGRAPH + t];
        lcnt[t] = 0;
        if (h == 0) offsets[t] = offs;
    }
    __syncthreads();
    for (int i = t; i < CHUNK_I4; i += 256) {
        int e4 = h * CHUNK_I4 + i;
        int4 r4 = ((const int4*)row)[e4];
        int4 c4 = ((const int4*)col)[e4];
        int rr[4] = {r4.x, r4.y, r4.z, r4.w};
        int cc[4] = {c4.x, c4.y, c4.z, c4.w};
#pragma unroll
        for (int u = 0; u < 4; ++u) {
            int g = rr[u] / perG;
            int lpos = atomicAdd(&lcnt[g], 1);
            sorted[(size_t)base_[g] + lpos] = make_uint2((unsigned)rr[u], (unsigned)cc[u]);
        }
    }
}

// ---- adj: flat 2048 blocks, XCD-swizzled. INLINE-ASM pipelined gathers:
// per 8-edge group, issue all 16 global loads via volatile asm (SGPR base +
// VGPR offset), ONE s_waitcnt vmcnt(0) + sched_barrier(0), then 40 FMAs.
// hipcc can't re-fuse asm loads to uses (rounds 12-14: VGPR pinned at 40,
// ~123cy/edge of serialized latency) -> ~16 loads in flight, ~27cy/edge.
__global__ __launch_bounds__(256) void k_adj(const uint2* __restrict__ sorted,
                                             const int* __restrict__ offsets,
                                             const int* __restrict__ gtot,
                                             const float* __restrict__ sel,
                                             float* __restrict__ dense_raw,
                                             float* __restrict__ den) {
    int b = blockIdx.x;
    int xcd = b & (NXCD - 1);
    int idx = b >> 3;
    int g = xcd * (NGRAPH / NXCD) + (idx >> 5);
    int split = idx & (ADJ_SPLIT - 1);

    int start = offsets[g];
    int cnt = gtot[g];
    int wavesPerGraph = ADJ_SPLIT * 4;        // 128
    int wid = threadIdx.x >> 6;
    int wseq = split * 4 + wid;
    int lane = threadIdx.x & 63;
    int i4 = (lane >> 2) * 4;                 // byte offset of a-word
    int j16 = (lane & 3) * 16;                // byte offset of b-float4

    float ax = 0.f, ay = 0.f, az = 0.f, aw = 0.f, qacc = 0.f;
    int nBatch = (cnt + 63) >> 6;
    for (int bb = wseq; bb < nBatch; bb += wavesPerGraph) {
        int e0 = bb << 6;
        int nb = cnt - e0;
        if (nb > 64) nb = 64;
        uint2 pr = sorted[start + e0 + (lane < nb ? lane : nb - 1)];
        int rxb = (int)pr.x << 6;             // node byte base (16 floats * 4B)
        int cxb = (int)pr.y << 6;
        int ee = 0;
        for (; ee + 8 <= nb; ee += 8) {
            float a_[8];
            vfloat4 b_[8];
#pragma unroll
            for (int u = 0; u < 8; ++u) {
                int rb = __builtin_amdgcn_readlane(rxb, ee + u);
                int cb = __builtin_amdgcn_readlane(cxb, ee + u);
                asm volatile("global_load_dword %0, %1, %2"
                             : "=v"(a_[u]) : "v"(rb + i4), "s"(sel));
                asm volatile("global_load_dwordx4 %0, %1, %2"
                             : "=v"(b_[u]) : "v"(cb + j16), "s"(sel));
            }
            asm volatile("s_waitcnt vmcnt(0)" ::: "memory");
            __builtin_amdgcn_sched_barrier(0);
#pragma unroll
            for (int u = 0; u < 8; ++u) {
                ax = fmaf(a_[u], b_[u][0], ax);
                ay = fmaf(a_[u], b_[u][1], ay);
                az = fmaf(a_[u], b_[u][2], az);
                aw = fmaf(a_[u], b_[u][3], aw);
                qacc = fmaf(a_[u], a_[u], qacc);
            }
        }
        for (; ee < nb; ++ee) {
            int rb = __builtin_amdgcn_readlane(rxb, ee);
            int cb = __builtin_amdgcn_readlane(cxb, ee);
            float a = *(const float*)((const char*)sel + rb + i4);
            float4 bv = *(const float4*)((const char*)sel + cb + j16);
            ax = fmaf(a, bv.x, ax);
            ay = fmaf(a, bv.y, ay);
            az = fmaf(a, bv.z, az);
            aw = fmaf(a, bv.w, aw);
            qacc = fmaf(a, a, qacc);
        }
    }
    __shared__ float lacc[4][256];
    __shared__ float qred[4];
    *(float4*)&lacc[wid][(i4 >> 2) * K_DIMC + (j16 >> 2)] = make_float4(ax, ay, az, aw);
#pragma unroll
    for (int off = 32; off > 0; off >>= 1) qacc += __shfl_down(qacc, off);
    if (lane == 0) qred[wid] = qacc;
    __syncthreads();
    int t = threadIdx.x;
    float s = lacc[0][t] + lacc[1][t] + lacc[2][t] + lacc[3][t];
    atomicAdd(dense_raw + g * 256 + t, s);
    if (t == 0) {
        float qs = (qred[0] + qred[1] + qred[2] + qred[3]) * 0.25f;
        atomicAdd(den + g, qs);
    }
}

// ---- SX/SS: grid (SX_SPLIT, NGRAPH), 8 waves ----
__global__ __launch_bounds__(512) void k_sx(const float* __restrict__ sel,
                                            const float* __restrict__ x,
                                            float* __restrict__ ssbuf,
                                            float* __restrict__ sxbuf, int perG) {
    int g = blockIdx.y;
    int wid = threadIdx.x >> 6;
    int wslot = blockIdx.x * SX_WAVES + wid;     // 0..63
    int lane = threadIdx.x & 63;
    int k = lane >> 2;
    int sub = lane & 3;
    int f0 = sub * 16;
    int j0 = sub * 4;
    float accss[4] = {0.f, 0.f, 0.f, 0.f};
    float accsx[16];
#pragma unroll
    for (int j = 0; j < 16; ++j) accsx[j] = 0.f;
    size_t base = (size_t)g * perG;
    int stride = SX_SPLIT * SX_WAVES;            // 64
#pragma unroll 2
    for (int nn = wslot; nn < perG; nn += stride) {
        size_t node = base + nn;
        float a = sel[node * K_DIMC + k];
        float4 s4 = *(const float4*)(sel + node * K_DIMC + j0);
        accss[0] += a * s4.x;
        accss[1] += a * s4.y;
        accss[2] += a * s4.z;
        accss[3] += a * s4.w;
        const float4* xv = (const float4*)(x + node * F_DIMC + f0);
#pragma unroll
        for (int j = 0; j < 4; ++j) {
            float4 v = xv[j];
            accsx[4 * j + 0] += a * v.x;
            accsx[4 * j + 1] += a * v.y;
            accsx[4 * j + 2] += a * v.z;
            accsx[4 * j + 3] += a * v.w;
        }
    }
    __shared__ float lsx[SX_WAVES][K_DIMC * F_DIMC];  // 32 KB
    __shared__ float lss[SX_WAVES][256];              // 8 KB
#pragma unroll
    for (int j4 = 0; j4 < 4; ++j4) {
        *(float4*)&lsx[wid][k * F_DIMC + f0 + 4 * j4] =
            make_float4(accsx[4 * j4], accsx[4 * j4 + 1], accsx[4 * j4 + 2], accsx[4 * j4 + 3]);
    }
    *(float4*)&lss[wid][k * K_DIMC + j0] = make_float4(accss[0], accss[1], accss[2], accss[3]);
    __syncthreads();
    for (int c = threadIdx.x; c < K_DIMC * F_DIMC; c += 512) {
        float s = 0.f;
#pragma unroll
        for (int w = 0; w < SX_WAVES; ++w) s += lsx[w][c];
        atomicAdd(sxbuf + (size_t)g * (K_DIMC * F_DIMC) + c, s);
    }
    if (threadIdx.x < 256) {
        int c = threadIdx.x;
        float s = 0.f;
#pragma unroll
        for (int w = 0; w < SX_WAVES; ++w) s += lss[w][c];
        atomicAdd(ssbuf + g * 256 + c, s);
    }
}

// ---- finalize: normalize adj, copy SX to out, losses via ws + last-block write ----
__global__ __launch_bounds__(256) void k_fin(const float* __restrict__ dense_raw,
                                             const float* __restrict__ ssbuf,
                                             const float* __restrict__ sxbuf,
                                             const float* __restrict__ den,
                                             float* __restrict__ lossws,
                                             int* __restrict__ donecnt,
                                             float* __restrict__ out) {
    int g = blockIdx.x;
    int c = threadIdx.x;
    int k = c >> 4, j = c & 15;
    int lane = threadIdx.x & 63;
    int wid = threadIdx.x >> 6;

    ((float4*)(out + (size_t)g * (K_DIMC * F_DIMC)))[c] =
        ((const float4*)(sxbuf + (size_t)g * (K_DIMC * F_DIMC)))[c];

    float a = dense_raw[g * 256 + c];
    float s = a;
    s += __shfl_xor(s, 1);
    s += __shfl_xor(s, 2);
    s += __shfl_xor(s, 4);
    s += __shfl_xor(s, 8);
    __shared__ float dvrow[K_DIMC];
    if (j == 0) dvrow[k] = sqrtf(s) + 1e-15f;
    __syncthreads();
    float v = a / (dvrow[k] * dvrow[j]);
    out[ADJ_OFF + g * 256 + c] = v;

    float ss = ssbuf[g * 256 + c];
    float tt = (k == j) ? v : 0.f;
    float n2 = ss * ss;
#pragma unroll
    for (int off = 32; off > 0; off >>= 1) {
        tt += __shfl_down(tt, off);
        n2 += __shfl_down(n2, off);
    }
    __shared__ float redt[4], redn[4];
    if (lane == 0) { redt[wid] = tt; redn[wid] = n2; }
    __syncthreads();
    float tr = redt[0] + redt[1] + redt[2] + redt[3];
    float nrm2 = redn[0] + redn[1] + redn[2] + redn[3];
    float invn = 1.f / sqrtf(nrm2);
    float d = ss * invn - ((k == j) ? 0.25f : 0.f);
    float o2 = d * d;
#pragma unroll
    for (int off = 32; off > 0; off >>= 1) o2 += __shfl_down(o2, off);
    __shared__ float redo[4];
    if (lane == 0) redo[wid] = o2;
    __syncthreads();
    if (threadIdx.x == 0) {
        float osum = redo[0] + redo[1] + redo[2] + redo[3];
        float og = sqrtf(osum);
        float mterm = -(tr / den[g]);
        atomicAdd(lossws + 0, mterm * (1.f / NGRAPH));
        atomicAdd(lossws + 1, og * (1.f / NGRAPH));
        __threadfence();
        int old = atomicAdd(donecnt, 1);
        if (old == NGRAPH - 1) {
            float l0 = atomicAdd(lossws + 0, 0.f);
            float l1 = atomicAdd(lossws + 1, 0.f);
            out[LOSS_OFF + 0] = l0;
            out[LOSS_OFF + 1] = l1;
        }
    }
}

extern "C" void kernel_launch(void* const* d_in, const int* in_sizes, int n_in,
                              void* d_out, int out_size, void* d_ws, size_t ws_size,
                              hipStream_t stream) {
    const float* node_attr = (const float*)d_in[0];
    const float* W = (const float*)d_in[1];
    const float* bias = (const float*)d_in[2];
    const int* edge_index = (const int*)d_in[3];
    int N = in_sizes[0] / F_DIMC;
    int E = in_sizes[3] / 2;
    int perG = N / NGRAPH;
    const int* row = edge_index;
    const int* col = edge_index + E;
    float* out = (float*)d_out;
    char* ws = (char*)d_ws;

    float* den = (float*)(ws + 0);
    int* donecnt = (int*)(ws + 256);
    float* lossws = (float*)(ws + 512);
    float* dense_raw = (float*)(ws + 1024);
    float* ssbuf = (float*)(ws + 66560);
    float* sxbuf = (float*)(ws + 132096);
    int* offsets = (int*)(ws + 394240);
    int* gtot = (int*)(ws + 394496);
    int* blockhist = (int*)(ws + 394752);
    int* chunkbase = (int*)(ws + 460288);
    float* sel = (float*)(ws + 525824);
    uint2* sorted = (uint2*)(ws + 7079424);

    k_zero<<<64, 256, 0, stream>>>((float4*)ws, ZERO_BYTES / 16);
    k_sel_hist<<<NB_SEL + NB_CHUNK, 256, 0, stream>>>(node_attr, W, bias, row, sel,
                                                      blockhist, N, perG);
    k_chunkscan<<<NGRAPH, 256, 0, stream>>>(blockhist, chunkbase, gtot);
    k_scatter<<<NB_CHUNK, 256, 0, stream>>>(row, col, gtot, chunkbase, offsets,
                                            sorted, perG);
    k_adj<<<ADJ_SPLIT * NGRAPH, 256, 0, stream>>>(sorted, offsets, gtot, sel, dense_raw, den);
    k_sx<<<dim3(SX_SPLIT, NGRAPH), 512, 0, stream>>>(sel, node_attr, ssbuf, sxbuf, perG);
    k_fin<<<NGRAPH, 256, 0, stream>>>(dense_raw, ssbuf, sxbuf, den, lossws, donecnt, out);
}

// Round 18
// 103.307 us; speedup vs baseline: 3.5286x; 1.0183x over previous
//
#include <hip/hip_runtime.h>

#define F_DIMC 64
#define K_DIMC 16
#define NGRAPH 64
#define NXCD 8
#define PERG 1600
#define SX_WAVES 8
#define SX_SPLIT 8
#define NB_SEL 400                         // N/256
#define NB_CHUNK 256                       // histogram/scatter chunks
#define NB_ZERO 64
#define CHUNK_I4 800                       // int4s per chunk (256*800 = E/4)
#define ADJ_BLOCKS 256                     // 1/CU, 4/graph
#define ADJ_OFF (NGRAPH * K_DIMC * F_DIMC)
#define LOSS_OFF (ADJ_OFF + NGRAPH * K_DIMC * K_DIMC)
#define ZERO_BYTES 394240

typedef __attribute__((ext_vector_type(4))) float vfloat4;

// ---------------- workspace layout (bytes) ----------------
// zeroed each call (by zero-role blocks of k_sel_hist): [0, 394240)
//   [0,256) den | [256,512) donecnt | [512,768) lossws | [768,1024) pad
//   [1024,66560) dense_raw | [66560,132096) ssbuf | [132096,394240) sxbuf
// not zeroed:
//   [394240,394496) offsets | [394496,394752) gtot
//   [394752,460288) blockhist | [460288,525824) chunkbase
//   [525824,7079424) sel (float[N*16]) | [7079424,13633024) sorted (uint2[E])

// ---- fused: selection [0,NB_SEL) || per-chunk histogram || ws zeroing ----
__global__ __launch_bounds__(256) void k_sel_hist(const float* __restrict__ node_attr,
                                                  const float* __restrict__ W,
                                                  const float* __restrict__ bias,
                                                  const int* __restrict__ row,
                                                  float* __restrict__ sel,
                                                  int* __restrict__ blockhist,
                                                  float4* __restrict__ zdst,
                                                  int N, int perG) {
    int t = threadIdx.x;
    if (blockIdx.x < NB_SEL) {
        __shared__ float sW[K_DIMC][F_DIMC];
        __shared__ float sb[K_DIMC];
        for (int idx = t; idx < F_DIMC * K_DIMC; idx += 256) {
            int f = idx / K_DIMC, k = idx % K_DIMC;
            sW[k][f] = W[idx];
        }
        if (t < K_DIMC) sb[t] = bias[t];
        __syncthreads();
        int n = blockIdx.x * 256 + t;
        if (n >= N) return;

        const float4* xr = (const float4*)(node_attr + (size_t)n * F_DIMC);
        float4 x[F_DIMC / 4];
#pragma unroll
        for (int f4 = 0; f4 < F_DIMC / 4; ++f4) x[f4] = xr[f4];

        float logits[K_DIMC];
#pragma unroll
        for (int k = 0; k < K_DIMC; ++k) {
            const float4* wk = (const float4*)&sW[k][0];
            float acc = sb[k];
#pragma unroll
            for (int f4 = 0; f4 < F_DIMC / 4; ++f4) {
                float4 w = wk[f4];
                acc += x[f4].x * w.x + x[f4].y * w.y + x[f4].z * w.z + x[f4].w * w.w;
            }
            logits[k] = acc;
        }
        float m = logits[0];
#pragma unroll
        for (int k = 1; k < K_DIMC; ++k) m = fmaxf(m, logits[k]);
        float sum = 0.f;
#pragma unroll
        for (int k = 0; k < K_DIMC; ++k) {
            float e = __expf(logits[k] - m);
            logits[k] = e;
            sum += e;
        }
        float inv = 1.f / sum;
        float4* sd = (float4*)(sel + (size_t)n * K_DIMC);
#pragma unroll
        for (int k4 = 0; k4 < K_DIMC / 4; ++k4) {
            float4 v;
            v.x = logits[4 * k4 + 0] * inv;
            v.y = logits[4 * k4 + 1] * inv;
            v.z = logits[4 * k4 + 2] * inv;
            v.w = logits[4 * k4 + 3] * inv;
            sd[k4] = v;
        }
    } else if (blockIdx.x < NB_SEL + NB_CHUNK) {
        __shared__ int lh[NGRAPH];
        int h = blockIdx.x - NB_SEL;                 // 0..255, static chunk
        if (t < NGRAPH) lh[t] = 0;
        __syncthreads();
        for (int i = t; i < CHUNK_I4; i += 256) {
            int4 r4 = ((const int4*)row)[h * CHUNK_I4 + i];
            atomicAdd(&lh[r4.x / perG], 1);
            atomicAdd(&lh[r4.y / perG], 1);
            atomicAdd(&lh[r4.z / perG], 1);
            atomicAdd(&lh[r4.w / perG], 1);
        }
        __syncthreads();
        if (t < NGRAPH) blockhist[h * NGRAPH + t] = lh[t];
    } else {
        // ws zeroing role (consumed only by LATER kernels)
        int z = blockIdx.x - NB_SEL - NB_CHUNK;
        for (int i = z * 256 + t; i < ZERO_BYTES / 16; i += NB_ZERO * 256)
            zdst[i] = make_float4(0.f, 0.f, 0.f, 0.f);
    }
}

// ---- per-graph exclusive scan over 256 chunks: chunkbase[b][g], gtot[g] ----
__global__ __launch_bounds__(256) void k_chunkscan(const int* __restrict__ blockhist,
                                                   int* __restrict__ chunkbase,
                                                   int* __restrict__ gtot) {
    int g = blockIdx.x;
    int t = threadIdx.x;                 // 0..255 = chunk index
    int lane = t & 63;
    int wid = t >> 6;
    int v = blockhist[t * NGRAPH + g];
    int s = v;
#pragma unroll
    for (int d = 1; d < 64; d <<= 1) {
        int o = __shfl_up(s, d);
        if (lane >= d) s += o;
    }
    __shared__ int wsum[4];
    if (lane == 63) wsum[wid] = s;
    __syncthreads();
    int pre = 0;
#pragma unroll
    for (int w = 0; w < 4; ++w) pre += (w < wid) ? wsum[w] : 0;
    int incl = s + pre;
    chunkbase[t * NGRAPH + g] = incl - v;
    if (t == 255) gtot[g] = incl;
}

// ---- deterministic scatter: static chunks; LDS position counters only ----
__global__ __launch_bounds__(256) void k_scatter(const int* __restrict__ row,
                                                 const int* __restrict__ col,
                                                 const int* __restrict__ gtot,
                                                 const int* __restrict__ chunkbase,
                                                 int* __restrict__ offsets,
                                                 uint2* __restrict__ sorted,
                                                 int perG) {
    __shared__ int base_[NGRAPH];
    __shared__ int lcnt[NGRAPH];
    int t = threadIdx.x;
    int h = blockIdx.x;                  // 0..255, same chunk as hist
    if (t < 64) {
        int v = gtot[t];
        int s = v;
#pragma unroll
        for (int d = 1; d < 64; d <<= 1) {
            int o = __shfl_up(s, d);
            if (t >= d) s += o;
        }
        int offs = s - v;                // exclusive scan = graph base
        base_[t] = offs + chunkbase[h * NGRAPH + t];
        lcnt[t] = 0;
        if (h == 0) offsets[t] = offs;
    }
    __syncthreads();
    for (int i = t; i < CHUNK_I4; i += 256) {
        int e4 = h * CHUNK_I4 + i;
        int4 r4 = ((const int4*)row)[e4];
        int4 c4 = ((const int4*)col)[e4];
        int rr[4] = {r4.x, r4.y, r4.z, r4.w};
        int cc[4] = {c4.x, c4.y, c4.z, c4.w};
#pragma unroll
        for (int u = 0; u < 4; ++u) {
            int g = rr[u] / perG;
            int lpos = atomicAdd(&lcnt[g], 1);
            sorted[(size_t)base_[g] + lpos] = make_uint2((unsigned)rr[u], (unsigned)cc[u]);
        }
    }
}

// ---- adj DUAL-PIPE: 256 blocks (1/CU, 4/graph), 512 thr, sel staged in LDS.
// Odd waves gather from LDS (ds pipe, ~18cy/edge); even waves gather from
// global via asm deep-pipeline (TA/VMEM pipe, 16 loads in flight to self-hide
// latency at only 4 waves/CU). Rounds 12-17: each pipe alone bottoms at
// ~40us (per-CU instruction throughput wall); in parallel -> ~max(21,12)us.
__global__ __launch_bounds__(512) void k_adj(const uint2* __restrict__ sorted,
                                             const int* __restrict__ offsets,
                                             const int* __restrict__ gtot,
                                             const float* __restrict__ sel,
                                             float* __restrict__ dense_raw,
                                             float* __restrict__ den) {
    __shared__ float selg[PERG * K_DIMC];    // 102400 B
    __shared__ float qred[8];
    int b = blockIdx.x;                      // 0..255
    int xcd = b & (NXCD - 1);
    int idx = b >> 3;                        // 0..31
    int g = xcd * (NGRAPH / NXCD) + (idx >> 2);
    int split = idx & 3;
    int t = threadIdx.x;

    {   // stage graph's sel slice (coalesced, L2-hot)
        const float4* src = (const float4*)(sel + (size_t)g * PERG * K_DIMC);
        float4* dst = (float4*)selg;
        for (int i4 = t; i4 < PERG * K_DIMC / 4; i4 += 512) dst[i4] = src[i4];
    }
    __syncthreads();

    int start = offsets[g];
    int cnt = gtot[g];
    int wid = t >> 6;
    int lane = t & 63;
    int wslot = split * 8 + wid;             // 0..31
    int i = lane >> 2;
    int j0 = (lane & 3) * 4;
    int i4b = i * 4;                         // byte offsets for asm path
    int j16b = (lane & 3) * 16;
    int gbase16 = g * PERG * K_DIMC;
    bool useLds = (wid & 1);

    float ax = 0.f, ay = 0.f, az = 0.f, aw = 0.f, qacc = 0.f;
    int nBatch = (cnt + 63) >> 6;
    for (int bb = wslot; bb < nBatch; bb += 32) {
        int e0 = bb << 6;
        int nb = cnt - e0;
        if (nb > 64) nb = 64;
        uint2 pr = sorted[start + e0 + (lane < nb ? lane : nb - 1)];
        if (useLds) {
            int rx = (int)(pr.x * K_DIMC) - gbase16;
            int cx = (int)(pr.y * K_DIMC) - gbase16;
#pragma unroll 8
            for (int ee = 0; ee < nb; ++ee) {
                int rb = __builtin_amdgcn_readlane(rx, ee);
                int cb = __builtin_amdgcn_readlane(cx, ee);
                float a = selg[rb + i];
                float4 bv = *(const float4*)&selg[cb + j0];
                ax = fmaf(a, bv.x, ax);
                ay = fmaf(a, bv.y, ay);
                az = fmaf(a, bv.z, az);
                aw = fmaf(a, bv.w, aw);
                qacc = fmaf(a, a, qacc);
            }
        } else {
            int rxb = (int)pr.x << 6;        // byte base
            int cxb = (int)pr.y << 6;
            int ee = 0;
            for (; ee + 8 <= nb; ee += 8) {
                float a_[8];
                vfloat4 b_[8];
#pragma unroll
                for (int u = 0; u < 8; ++u) {
                    int rb = __builtin_amdgcn_readlane(rxb, ee + u);
                    int cb = __builtin_amdgcn_readlane(cxb, ee + u);
                    asm volatile("global_load_dword %0, %1, %2"
                                 : "=v"(a_[u]) : "v"(rb + i4b), "s"(sel));
                    asm volatile("global_load_dwordx4 %0, %1, %2"
                                 : "=v"(b_[u]) : "v"(cb + j16b), "s"(sel));
                }
                asm volatile("s_waitcnt vmcnt(0)" ::: "memory");
                __builtin_amdgcn_sched_barrier(0);
#pragma unroll
                for (int u = 0; u < 8; ++u) {
                    ax = fmaf(a_[u], b_[u][0], ax);
                    ay = fmaf(a_[u], b_[u][1], ay);
                    az = fmaf(a_[u], b_[u][2], az);
                    aw = fmaf(a_[u], b_[u][3], aw);
                    qacc = fmaf(a_[u], a_[u], qacc);
                }
            }
            for (; ee < nb; ++ee) {
                int rb = __builtin_amdgcn_readlane(rxb, ee);
                int cb = __builtin_amdgcn_readlane(cxb, ee);
                float a = *(const float*)((const char*)sel + rb + i4b);
                float4 bv = *(const float4*)((const char*)sel + cb + j16b);
                ax = fmaf(a, bv.x, ax);
                ay = fmaf(a, bv.y, ay);
                az = fmaf(a, bv.z, az);
                aw = fmaf(a, bv.w, aw);
                qacc = fmaf(a, a, qacc);
            }
        }
    }
    // block reduce: alias reduction buffer into selg (done reading it)
    __syncthreads();
    float* lacc = selg;                      // [8][256]
    *(float4*)&lacc[wid * 256 + i * K_DIMC + j0] = make_float4(ax, ay, az, aw);
#pragma unroll
    for (int off = 32; off > 0; off >>= 1) qacc += __shfl_down(qacc, off);
    if (lane == 0) qred[wid] = qacc;
    __syncthreads();
    if (t < 256) {
        float s = 0.f;
#pragma unroll
        for (int w = 0; w < 8; ++w) s += lacc[w * 256 + t];
        atomicAdd(dense_raw + g * 256 + t, s);
    }
    if (t == 0) {
        float qs = 0.f;
#pragma unroll
        for (int w = 0; w < 8; ++w) qs += qred[w];
        atomicAdd(den + g, qs * 0.25f);
    }
}

// ---- SX/SS: grid (SX_SPLIT, NGRAPH), 8 waves ----
__global__ __launch_bounds__(512) void k_sx(const float* __restrict__ sel,
                                            const float* __restrict__ x,
                                            float* __restrict__ ssbuf,
                                            float* __restrict__ sxbuf, int perG) {
    int g = blockIdx.y;
    int wid = threadIdx.x >> 6;
    int wslot = blockIdx.x * SX_WAVES + wid;     // 0..63
    int lane = threadIdx.x & 63;
    int k = lane >> 2;
    int sub = lane & 3;
    int f0 = sub * 16;
    int j0 = sub * 4;
    float accss[4] = {0.f, 0.f, 0.f, 0.f};
    float accsx[16];
#pragma unroll
    for (int j = 0; j < 16; ++j) accsx[j] = 0.f;
    size_t base = (size_t)g * perG;
    int stride = SX_SPLIT * SX_WAVES;            // 64
#pragma unroll 2
    for (int nn = wslot; nn < perG; nn += stride) {
        size_t node = base + nn;
        float a = sel[node * K_DIMC + k];
        float4 s4 = *(const float4*)(sel + node * K_DIMC + j0);
        accss[0] += a * s4.x;
        accss[1] += a * s4.y;
        accss[2] += a * s4.z;
        accss[3] += a * s4.w;
        const float4* xv = (const float4*)(x + node * F_DIMC + f0);
#pragma unroll
        for (int j = 0; j < 4; ++j) {
            float4 v = xv[j];
            accsx[4 * j + 0] += a * v.x;
            accsx[4 * j + 1] += a * v.y;
            accsx[4 * j + 2] += a * v.z;
            accsx[4 * j + 3] += a * v.w;
        }
    }
    __shared__ float lsx[SX_WAVES][K_DIMC * F_DIMC];  // 32 KB
    __shared__ float lss[SX_WAVES][256];              // 8 KB
#pragma unroll
    for (int j4 = 0; j4 < 4; ++j4) {
        *(float4*)&lsx[wid][k * F_DIMC + f0 + 4 * j4] =
            make_float4(accsx[4 * j4], accsx[4 * j4 + 1], accsx[4 * j4 + 2], accsx[4 * j4 + 3]);
    }
    *(float4*)&lss[wid][k * K_DIMC + j0] = make_float4(accss[0], accss[1], accss[2], accss[3]);
    __syncthreads();
    for (int c = threadIdx.x; c < K_DIMC * F_DIMC; c += 512) {
        float s = 0.f;
#pragma unroll
        for (int w = 0; w < SX_WAVES; ++w) s += lsx[w][c];
        atomicAdd(sxbuf + (size_t)g * (K_DIMC * F_DIMC) + c, s);
    }
    if (threadIdx.x < 256) {
        int c = threadIdx.x;
        float s = 0.f;
#pragma unroll
        for (int w = 0; w < SX_WAVES; ++w) s += lss[w][c];
        atomicAdd(ssbuf + g * 256 + c, s);
    }
}

// ---- finalize: normalize adj, copy SX to out, losses via ws + last-block write ----
__global__ __launch_bounds__(256) void k_fin(const float* __restrict__ dense_raw,
                                             const float* __restrict__ ssbuf,
                                             const float* __restrict__ sxbuf,
                                             const float* __restrict__ den,
                                             float* __restrict__ lossws,
                                             int* __restrict__ donecnt,
                                             float* __restrict__ out) {
    int g = blockIdx.x;
    int c = threadIdx.x;
    int k = c >> 4, j = c & 15;
    int lane = threadIdx.x & 63;
    int wid = threadIdx.x >> 6;

    ((float4*)(out + (size_t)g * (K_DIMC * F_DIMC)))[c] =
        ((const float4*)(sxbuf + (size_t)g * (K_DIMC * F_DIMC)))[c];

    float a = dense_raw[g * 256 + c];
    float s = a;
    s += __shfl_xor(s, 1);
    s += __shfl_xor(s, 2);
    s += __shfl_xor(s, 4);
    s += __shfl_xor(s, 8);
    __shared__ float dvrow[K_DIMC];
    if (j == 0) dvrow[k] = sqrtf(s) + 1e-15f;
    __syncthreads();
    float v = a / (dvrow[k] * dvrow[j]);
    out[ADJ_OFF + g * 256 + c] = v;

    float ss = ssbuf[g * 256 + c];
    float tt = (k == j) ? v : 0.f;
    float n2 = ss * ss;
#pragma unroll
    for (int off = 32; off > 0; off >>= 1) {
        tt += __shfl_down(tt, off);
        n2 += __shfl_down(n2, off);
    }
    __shared__ float redt[4], redn[4];
    if (lane == 0) { redt[wid] = tt; redn[wid] = n2; }
    __syncthreads();
    float tr = redt[0] + redt[1] + redt[2] + redt[3];
    float nrm2 = redn[0] + redn[1] + redn[2] + redn[3];
    float invn = 1.f / sqrtf(nrm2);
    float d = ss * invn - ((k == j) ? 0.25f : 0.f);
    float o2 = d * d;
#pragma unroll
    for (int off = 32; off > 0; off >>= 1) o2 += __shfl_down(o2, off);
    __shared__ float redo[4];
    if (lane == 0) redo[wid] = o2;
    __syncthreads();
    if (threadIdx.x == 0) {
        float osum = redo[0] + redo[1] + redo[2] + redo[3];
        float og = sqrtf(osum);
        float mterm = -(tr / den[g]);
        atomicAdd(lossws + 0, mterm * (1.f / NGRAPH));
        atomicAdd(lossws + 1, og * (1.f / NGRAPH));
        __threadfence();
        int old = atomicAdd(donecnt, 1);
        if (old == NGRAPH - 1) {
            float l0 = atomicAdd(lossws + 0, 0.f);
            float l1 = atomicAdd(lossws + 1, 0.f);
            out[LOSS_OFF + 0] = l0;
            out[LOSS_OFF + 1] = l1;
        }
    }
}

extern "C" void kernel_launch(void* const* d_in, const int* in_sizes, int n_in,
                              void* d_out, int out_size, void* d_ws, size_t ws_size,
                              hipStream_t stream) {
    const float* node_attr = (const float*)d_in[0];
    const float* W = (const float*)d_in[1];
    const float* bias = (const float*)d_in[2];
    const int* edge_index = (const int*)d_in[3];
    int N = in_sizes[0] / F_DIMC;
    int E = in_sizes[3] / 2;
    int perG = N / NGRAPH;
    const int* row = edge_index;
    const int* col = edge_index + E;
    float* out = (float*)d_out;
    char* ws = (char*)d_ws;

    float* den = (float*)(ws + 0);
    int* donecnt = (int*)(ws + 256);
    float* lossws = (float*)(ws + 512);
    float* dense_raw = (float*)(ws + 1024);
    float* ssbuf = (float*)(ws + 66560);
    float* sxbuf = (float*)(ws + 132096);
    int* offsets = (int*)(ws + 394240);
    int* gtot = (int*)(ws + 394496);
    int* blockhist = (int*)(ws + 394752);
    int* chunkbase = (int*)(ws + 460288);
    float* sel = (float*)(ws + 525824);
    uint2* sorted = (uint2*)(ws + 7079424);

    k_sel_hist<<<NB_SEL + NB_CHUNK + NB_ZERO, 256, 0, stream>>>(node_attr, W, bias, row, sel,
                                                                blockhist, (float4*)ws, N, perG);
    k_chunkscan<<<NGRAPH, 256, 0, stream>>>(blockhist, chunkbase, gtot);
    k_scatter<<<NB_CHUNK, 256, 0, stream>>>(row, col, gtot, chunkbase, offsets,
                                            sorted, perG);
    k_adj<<<ADJ_BLOCKS, 512, 0, stream>>>(sorted, offsets, gtot, sel, dense_raw, den);
    k_sx<<<dim3(SX_SPLIT, NGRAPH), 512, 0, stream>>>(sel, node_attr, ssbuf, sxbuf, perG);
    k_fin<<<NGRAPH, 256, 0, stream>>>(dense_raw, ssbuf, sxbuf, den, lossws, donecnt, out);
}